// Round 1
// baseline (1150.898 us; speedup 1.0000x reference)
//
#include <hip/hip_runtime.h>
#include <math.h>

#define N_NODES 20000
#define N_EDGES 256000

// ---------------- CSR build ----------------

__global__ void zero_ints(int* __restrict__ a, int n) {
    int i = blockIdx.x * blockDim.x + threadIdx.x;
    if (i < n) a[i] = 0;
}

__global__ void hist_kernel(const int* __restrict__ dst, int* __restrict__ deg) {
    int i = blockIdx.x * blockDim.x + threadIdx.x;
    if (i < N_EDGES) atomicAdd(&deg[dst[i]], 1);
}

// single-block inclusive scan -> exclusive offsets[N+1]
__global__ void scan_kernel(const int* __restrict__ deg, int* __restrict__ offsets) {
    __shared__ int red[256];
    __shared__ int s_total;
    int tid = threadIdx.x;
    if (tid == 0) { s_total = 0; offsets[0] = 0; }
    __syncthreads();
    for (int base = 0; base < N_NODES; base += 256) {
        int v = (base + tid < N_NODES) ? deg[base + tid] : 0;
        red[tid] = v;
        __syncthreads();
        for (int off = 1; off < 256; off <<= 1) {
            int t = (tid >= off) ? red[tid - off] : 0;
            __syncthreads();
            red[tid] += t;
            __syncthreads();
        }
        if (base + tid < N_NODES) offsets[base + tid + 1] = s_total + red[tid];
        __syncthreads();
        if (tid == 0) s_total += red[255];
        __syncthreads();
    }
}

__global__ void scatter_kernel(const int* __restrict__ dst, const int* __restrict__ offsets,
                               int* __restrict__ cursor, int* __restrict__ eidx) {
    int i = blockIdx.x * blockDim.x + threadIdx.x;
    if (i < N_EDGES) {
        int d = dst[i];
        int p = offsets[d] + atomicAdd(&cursor[d], 1);
        eidx[p] = i;
    }
}

// ---------------- GEMM (fp32, 64x64 tile, 256 thr, 4x4/thread) ----------------

#define BM 64
#define BN 64
#define BK 16

__global__ __launch_bounds__(256) void gemm_kernel(
    const float* __restrict__ A, const float* __restrict__ B,
    float* __restrict__ C, int M, int N, int K) {
    __shared__ float As[BK][BM + 4];
    __shared__ float Bs[BK][BN + 4];
    int tid = threadIdx.x;
    int tx = tid & 15, ty = tid >> 4;
    int m0 = blockIdx.y * BM, n0 = blockIdx.x * BN;
    float acc[4][4] = {};
    int arow = tid >> 2;       // 0..63
    int akc  = (tid & 3) * 4;  // 0,4,8,12
    int brow = tid >> 4;       // 0..15
    int bnc  = (tid & 15) * 4; // 0..60

    for (int k0 = 0; k0 < K; k0 += BK) {
        float4 av = make_float4(0.f, 0.f, 0.f, 0.f);
        if (m0 + arow < M)
            av = *(const float4*)(&A[(size_t)(m0 + arow) * K + k0 + akc]);
        As[akc][arow]     = av.x;
        As[akc + 1][arow] = av.y;
        As[akc + 2][arow] = av.z;
        As[akc + 3][arow] = av.w;
        float4 bv = make_float4(0.f, 0.f, 0.f, 0.f);
        if (n0 + bnc < N)
            bv = *(const float4*)(&B[(size_t)(k0 + brow) * N + n0 + bnc]);
        *(float4*)(&Bs[brow][bnc]) = bv;
        __syncthreads();
#pragma unroll
        for (int k = 0; k < BK; ++k) {
            float4 a = *(const float4*)(&As[k][ty * 4]);
            float4 b = *(const float4*)(&Bs[k][tx * 4]);
            float aa[4] = {a.x, a.y, a.z, a.w};
            float bb[4] = {b.x, b.y, b.z, b.w};
#pragma unroll
            for (int i = 0; i < 4; ++i)
#pragma unroll
                for (int j = 0; j < 4; ++j) acc[i][j] += aa[i] * bb[j];
        }
        __syncthreads();
    }
#pragma unroll
    for (int i = 0; i < 4; ++i) {
        int m = m0 + ty * 4 + i;
        if (m >= M) continue;
#pragma unroll
        for (int j = 0; j < 4; ++j) {
            int n = n0 + tx * 4 + j;
            if (n < N) C[(size_t)m * N + n] = acc[i][j];
        }
    }
}

// ---------------- attention left/right dot products ----------------
// block = H*64 threads, one node per block; wave w handles head w.
__global__ void elr_kernel(const float* __restrict__ h, const float* __restrict__ al,
                           const float* __restrict__ ar, float* __restrict__ el,
                           float* __restrict__ er, int H, int F) {
    int n = blockIdx.x;
    int lane = threadIdx.x & 63;
    int hh = threadIdx.x >> 6;
    const float* row = h + (size_t)n * H * F + (size_t)hh * F;
    float sl = 0.f, sr = 0.f;
    for (int f = lane; f < F; f += 64) {
        float v = row[f];
        sl += v * al[hh * F + f];
        sr += v * ar[hh * F + f];
    }
#pragma unroll
    for (int off = 32; off; off >>= 1) {
        sl += __shfl_down(sl, off);
        sr += __shfl_down(sr, off);
    }
    if (lane == 0) {
        el[n * H + hh] = sl;
        er[n * H + hh] = sr;
    }
}

// ---------------- per-edge leaky-relu scores ----------------
__global__ void escore_kernel(const int* __restrict__ src, const int* __restrict__ dst,
                              const float* __restrict__ el, const float* __restrict__ er,
                              float* __restrict__ esc, int H) {
    int i = blockIdx.x * blockDim.x + threadIdx.x;
    if (i >= N_EDGES * H) return;
    int e = i / H, hh = i - e * H;
    float v = el[src[e] * H + hh] + er[dst[e] * H + hh];
    esc[i] = v > 0.f ? v : 0.2f * v;
}

// ---------------- per-dst softmax + weighted aggregation ----------------
// one 256-thread block per dst node. ACT: 0 = ELU, 1 = sigmoid.
template <int ACT>
__global__ __launch_bounds__(256) void aggregate_kernel(
    const float* __restrict__ h, const float* __restrict__ esc,
    const int* __restrict__ offsets, const int* __restrict__ eidx,
    const int* __restrict__ src, const float* __restrict__ bias,
    float* __restrict__ out, int H, int F) {
    int n = blockIdx.x;
    int HF = H * F;
    int tid = threadIdx.x;
    int start = offsets[n];
    int deg = offsets[n + 1] - start;

    __shared__ float s_max[4];
    __shared__ float s_den[4];
    __shared__ float red[256];
    __shared__ float s_alpha[256];
    __shared__ int s_src[64];

    // phase 1: per-head max
    float lv[4];
#pragma unroll
    for (int hh = 0; hh < 4; ++hh) lv[hh] = -3.402823466e38f;
    for (int k = tid; k < deg; k += 256) {
        int e = eidx[start + k];
        for (int hh = 0; hh < H; ++hh) lv[hh] = fmaxf(lv[hh], esc[e * H + hh]);
    }
    for (int hh = 0; hh < H; ++hh) {
        red[tid] = lv[hh];
        __syncthreads();
        for (int s = 128; s; s >>= 1) {
            if (tid < s) red[tid] = fmaxf(red[tid], red[tid + s]);
            __syncthreads();
        }
        if (tid == 0) s_max[hh] = red[0];
        __syncthreads();
    }

    // phase 2: per-head sum of exp
    float ls[4] = {0.f, 0.f, 0.f, 0.f};
    for (int k = tid; k < deg; k += 256) {
        int e = eidx[start + k];
        for (int hh = 0; hh < H; ++hh) ls[hh] += expf(esc[e * H + hh] - s_max[hh]);
    }
    for (int hh = 0; hh < H; ++hh) {
        red[tid] = ls[hh];
        __syncthreads();
        for (int s = 128; s; s >>= 1) {
            if (tid < s) red[tid] += red[tid + s];
            __syncthreads();
        }
        if (tid == 0) s_den[hh] = red[0] + 1e-9f;
        __syncthreads();
    }

    // phase 3: weighted gather, 64-edge chunks
    float acc[4] = {0.f, 0.f, 0.f, 0.f};
    int hidx[4];
#pragma unroll
    for (int j = 0; j < 4; ++j) {
        int f = tid + j * 256;
        hidx[j] = (f < HF) ? f / F : 0;
    }
    for (int c0 = 0; c0 < deg; c0 += 64) {
        int cn = min(64, deg - c0);
        if (tid < cn) s_src[tid] = src[eidx[start + c0 + tid]];
        if (tid < cn * H) {
            int k = tid / H, hh = tid - (tid / H) * H;
            int e = eidx[start + c0 + k];
            s_alpha[tid] = expf(esc[e * H + hh] - s_max[hh]) / s_den[hh];
        }
        __syncthreads();
        for (int k = 0; k < cn; ++k) {
            const float* hrow = h + (size_t)s_src[k] * HF;
#pragma unroll
            for (int j = 0; j < 4; ++j) {
                int f = tid + j * 256;
                if (f < HF) acc[j] += hrow[f] * s_alpha[k * H + hidx[j]];
            }
        }
        __syncthreads();
    }

    // epilogue: + bias, activation
#pragma unroll
    for (int j = 0; j < 4; ++j) {
        int f = tid + j * 256;
        if (f < HF) {
            float v = acc[j] + bias[f];
            if (ACT == 0)
                v = v > 0.f ? v : expm1f(v);
            else
                v = 1.f / (1.f + expf(-v));
            out[(size_t)n * HF + f] = v;
        }
    }
}

// ---------------- launch ----------------

extern "C" void kernel_launch(void* const* d_in, const int* in_sizes, int n_in,
                              void* d_out, int out_size, void* d_ws, size_t ws_size,
                              hipStream_t stream) {
    const float* x   = (const float*)d_in[0];
    const int*   src = (const int*)d_in[1];
    const int*   dst = (const int*)d_in[2];
    const float* W1  = (const float*)d_in[3];
    const float* al1 = (const float*)d_in[4];
    const float* ar1 = (const float*)d_in[5];
    const float* b1  = (const float*)d_in[6];
    const float* W2  = (const float*)d_in[7];
    const float* al2 = (const float*)d_in[8];
    const float* ar2 = (const float*)d_in[9];
    const float* b2  = (const float*)d_in[10];
    const float* W3  = (const float*)d_in[11];
    const float* al3 = (const float*)d_in[12];
    const float* ar3 = (const float*)d_in[13];
    const float* b3  = (const float*)d_in[14];
    float* out = (float*)d_out;

    char* ws = (char*)d_ws;
    size_t off = 0;
    auto alloc = [&](size_t bytes) -> char* {
        char* p = ws + off;
        off += (bytes + 255) & ~(size_t)255;
        return p;
    };
    int* offsets = (int*)alloc((N_NODES + 1) * sizeof(int));
    int* cursor  = (int*)alloc(N_NODES * sizeof(int));
    int* deg     = (int*)alloc(N_NODES * sizeof(int));
    int* eidx    = (int*)alloc(N_EDGES * sizeof(int));
    float* el    = (float*)alloc((size_t)N_NODES * 4 * sizeof(float));
    float* er    = (float*)alloc((size_t)N_NODES * 4 * sizeof(float));
    float* esc   = (float*)alloc((size_t)N_EDGES * 4 * sizeof(float));
    float* bufA  = (float*)alloc((size_t)N_NODES * 800 * sizeof(float));
    float* bufB  = (float*)alloc((size_t)N_NODES * 800 * sizeof(float));

    // CSR build (dst-indexed)
    zero_ints<<<(N_NODES + 255) / 256, 256, 0, stream>>>(deg, N_NODES);
    zero_ints<<<(N_NODES + 255) / 256, 256, 0, stream>>>(cursor, N_NODES);
    hist_kernel<<<(N_EDGES + 255) / 256, 256, 0, stream>>>(dst, deg);
    scan_kernel<<<1, 256, 0, stream>>>(deg, offsets);
    scatter_kernel<<<(N_EDGES + 255) / 256, 256, 0, stream>>>(dst, offsets, cursor, eidx);

    // layer 1: [20000,128] @ [128,400], H=4 F=100, ELU
    {
        dim3 grid((400 + BN - 1) / BN, (N_NODES + BM - 1) / BM);
        gemm_kernel<<<grid, 256, 0, stream>>>(x, W1, bufA, N_NODES, 400, 128);
        elr_kernel<<<N_NODES, 4 * 64, 0, stream>>>(bufA, al1, ar1, el, er, 4, 100);
        escore_kernel<<<(N_EDGES * 4 + 255) / 256, 256, 0, stream>>>(src, dst, el, er, esc, 4);
        aggregate_kernel<0><<<N_NODES, 256, 0, stream>>>(bufA, esc, offsets, eidx, src, b1, bufB, 4, 100);
    }
    // layer 2: [20000,400] @ [400,800], H=4 F=200, ELU
    {
        dim3 grid((800 + BN - 1) / BN, (N_NODES + BM - 1) / BM);
        gemm_kernel<<<grid, 256, 0, stream>>>(bufB, W2, bufA, N_NODES, 800, 400);
        elr_kernel<<<N_NODES, 4 * 64, 0, stream>>>(bufA, al2, ar2, el, er, 4, 200);
        escore_kernel<<<(N_EDGES * 4 + 255) / 256, 256, 0, stream>>>(src, dst, el, er, esc, 4);
        aggregate_kernel<0><<<N_NODES, 256, 0, stream>>>(bufA, esc, offsets, eidx, src, b2, bufB, 4, 200);
    }
    // layer 3: [20000,800] @ [800,64], H=1 F=64, sigmoid -> d_out
    {
        dim3 grid((64 + BN - 1) / BN, (N_NODES + BM - 1) / BM);
        gemm_kernel<<<grid, 256, 0, stream>>>(bufB, W3, bufA, N_NODES, 64, 800);
        elr_kernel<<<N_NODES, 64, 0, stream>>>(bufA, al3, ar3, el, er, 1, 64);
        escore_kernel<<<(N_EDGES + 255) / 256, 256, 0, stream>>>(src, dst, el, er, esc, 1);
        aggregate_kernel<1><<<N_NODES, 256, 0, stream>>>(bufA, esc, offsets, eidx, src, b3, out, 1, 64);
    }
}

// Round 2
// 630.960 us; speedup vs baseline: 1.8240x; 1.8240x over previous
//
#include <hip/hip_runtime.h>
#include <math.h>

#define N_NODES 20000
#define N_EDGES 256000

typedef __attribute__((ext_vector_type(8))) short bf16x8;
typedef __attribute__((ext_vector_type(4))) float f32x4;

__device__ inline unsigned short f2b(float f) {
    unsigned u = __builtin_bit_cast(unsigned, f);
    unsigned r = (u + 0x7fffu + ((u >> 16) & 1u)) >> 16;
    return (unsigned short)r;
}

// ---------------- CSR build ----------------

__global__ void zero_ints(int* __restrict__ a, int n) {
    int i = blockIdx.x * blockDim.x + threadIdx.x;
    if (i < n) a[i] = 0;
}

__global__ void hist_kernel(const int* __restrict__ dst, int* __restrict__ deg) {
    int i = blockIdx.x * blockDim.x + threadIdx.x;
    if (i < N_EDGES) atomicAdd(&deg[dst[i]], 1);
}

__global__ void scan_kernel(const int* __restrict__ deg, int* __restrict__ offsets) {
    __shared__ int red[256];
    __shared__ int s_total;
    int tid = threadIdx.x;
    if (tid == 0) { s_total = 0; offsets[0] = 0; }
    __syncthreads();
    for (int base = 0; base < N_NODES; base += 256) {
        int v = (base + tid < N_NODES) ? deg[base + tid] : 0;
        red[tid] = v;
        __syncthreads();
        for (int off = 1; off < 256; off <<= 1) {
            int t = (tid >= off) ? red[tid - off] : 0;
            __syncthreads();
            red[tid] += t;
            __syncthreads();
        }
        if (base + tid < N_NODES) offsets[base + tid + 1] = s_total + red[tid];
        __syncthreads();
        if (tid == 0) s_total += red[255];
        __syncthreads();
    }
}

__global__ void scatter_kernel(const int* __restrict__ dst, const int* __restrict__ offsets,
                               int* __restrict__ cursor, int* __restrict__ eidx) {
    int i = blockIdx.x * blockDim.x + threadIdx.x;
    if (i < N_EDGES) {
        int d = dst[i];
        int p = offsets[d] + atomicAdd(&cursor[d], 1);
        eidx[p] = i;
    }
}

// ---------------- casts ----------------

__global__ void castx_kernel(const float* __restrict__ in, unsigned short* __restrict__ out, int n4) {
    int i = blockIdx.x * blockDim.x + threadIdx.x;
    if (i < n4) {
        float4 v = ((const float4*)in)[i];
        ushort4 u;
        u.x = f2b(v.x); u.y = f2b(v.y); u.z = f2b(v.z); u.w = f2b(v.w);
        ((ushort4*)out)[i] = u;
    }
}

// Wt[n][k] = bf16(W[k][n]); W is [K][N] row-major
__global__ void wcast_kernel(const float* __restrict__ W, unsigned short* __restrict__ Wt,
                             int K, int N) {
    int id = blockIdx.x * blockDim.x + threadIdx.x;
    if (id < K * N) {
        int n = id / K, k = id - n * K;
        Wt[id] = f2b(W[(size_t)k * N + n]);
    }
}

// ---------------- bf16 MFMA GEMM: C[M,N] = A[M,K] * Bt[N,K]^T ----------------
// 128x64 tile, BK=32, 4 waves (2x2), per-wave 64x32 (4x2 frags of 16x16x32)

#define LDK 40  // 32 + 8 pad (bf16 elems); row stride 80B, 16B-aligned

__global__ __launch_bounds__(256) void gemm_mfma(
    const unsigned short* __restrict__ A, const unsigned short* __restrict__ Bt,
    float* __restrict__ C, int M, int N, int K) {
    __shared__ short As[128 * LDK];
    __shared__ short Bs[64 * LDK];
    int tid = threadIdx.x;
    int m0 = blockIdx.y * 128, n0 = blockIdx.x * 64;
    int lane = tid & 63, wid = tid >> 6;
    int wm = wid >> 1, wn = wid & 1;
    int r16 = lane & 15, kg = lane >> 4, k8 = kg * 8;

    f32x4 zero4 = {0.f, 0.f, 0.f, 0.f};
    f32x4 acc[4][2];
#pragma unroll
    for (int m = 0; m < 4; ++m)
#pragma unroll
        for (int nn = 0; nn < 2; ++nn) acc[m][nn] = zero4;

    bf16x8 zv = {0, 0, 0, 0, 0, 0, 0, 0};

    for (int k0 = 0; k0 < K; k0 += 32) {
        // stage A: 128 rows x 32 cols = 512 chunks of 8 bf16
#pragma unroll
        for (int i = 0; i < 2; ++i) {
            int c = tid + i * 256;
            int row = c >> 2, off = (c & 3) * 8;
            bf16x8 v = zv;
            int gr = m0 + row, gc = k0 + off;
            if (gr < M && gc + 8 <= K)
                v = *(const bf16x8*)(const void*)(A + (size_t)gr * K + gc);
            *(bf16x8*)(void*)(&As[row * LDK + off]) = v;
        }
        // stage Bt: 64 rows x 32 cols = 256 chunks
        {
            int row = tid >> 2, off = (tid & 3) * 8;
            bf16x8 v = zv;
            int gr = n0 + row, gc = k0 + off;
            if (gr < N && gc + 8 <= K)
                v = *(const bf16x8*)(const void*)(Bt + (size_t)gr * K + gc);
            *(bf16x8*)(void*)(&Bs[row * LDK + off]) = v;
        }
        __syncthreads();
        bf16x8 a[4], b[2];
#pragma unroll
        for (int m = 0; m < 4; ++m)
            a[m] = *(const bf16x8*)(const void*)(&As[(wm * 64 + m * 16 + r16) * LDK + k8]);
#pragma unroll
        for (int nn = 0; nn < 2; ++nn)
            b[nn] = *(const bf16x8*)(const void*)(&Bs[(wn * 32 + nn * 16 + r16) * LDK + k8]);
#pragma unroll
        for (int m = 0; m < 4; ++m)
#pragma unroll
            for (int nn = 0; nn < 2; ++nn)
                acc[m][nn] = __builtin_amdgcn_mfma_f32_16x16x32_bf16(a[m], b[nn], acc[m][nn], 0, 0, 0);
        __syncthreads();
    }
    // C write: col = lane&15, row = (lane>>4)*4 + reg
#pragma unroll
    for (int m = 0; m < 4; ++m) {
        int row_base = m0 + wm * 64 + m * 16 + kg * 4;
#pragma unroll
        for (int nn = 0; nn < 2; ++nn) {
            int col = n0 + wn * 32 + nn * 16 + r16;
            if (col < N) {
#pragma unroll
                for (int r = 0; r < 4; ++r) {
                    int row = row_base + r;
                    if (row < M) C[(size_t)row * N + col] = acc[m][nn][r];
                }
            }
        }
    }
}

// ---------------- attention left/right dot products ----------------
__global__ void elr_kernel(const float* __restrict__ h, const float* __restrict__ al,
                           const float* __restrict__ ar, float* __restrict__ el,
                           float* __restrict__ er, int H, int F) {
    int n = blockIdx.x;
    int lane = threadIdx.x & 63;
    int hh = threadIdx.x >> 6;
    const float* row = h + (size_t)n * H * F + (size_t)hh * F;
    float sl = 0.f, sr = 0.f;
    for (int f = lane; f < F; f += 64) {
        float v = row[f];
        sl += v * al[hh * F + f];
        sr += v * ar[hh * F + f];
    }
#pragma unroll
    for (int off = 32; off; off >>= 1) {
        sl += __shfl_down(sl, off);
        sr += __shfl_down(sr, off);
    }
    if (lane == 0) {
        el[n * H + hh] = sl;
        er[n * H + hh] = sr;
    }
}

// ---------------- per-edge leaky-relu scores ----------------
__global__ void escore_kernel(const int* __restrict__ src, const int* __restrict__ dst,
                              const float* __restrict__ el, const float* __restrict__ er,
                              float* __restrict__ esc, int H) {
    int i = blockIdx.x * blockDim.x + threadIdx.x;
    if (i >= N_EDGES * H) return;
    int e = i / H, hh = i - e * H;
    float v = el[src[e] * H + hh] + er[dst[e] * H + hh];
    esc[i] = v > 0.f ? v : 0.2f * v;
}

// ---------------- per-dst segment max & denominator (one wave per node) ----------------
template <int H>
__global__ __launch_bounds__(64) void maxden_kernel(
    const float* __restrict__ esc, const int* __restrict__ offsets,
    const int* __restrict__ eidx, float* __restrict__ maxv, float* __restrict__ den) {
    int n = blockIdx.x;
    int lane = threadIdx.x;
    int start = offsets[n], deg = offsets[n + 1] - start;
    float m[H], s[H];
#pragma unroll
    for (int h = 0; h < H; ++h) { m[h] = -3.402823466e38f; s[h] = 0.f; }
    for (int c0 = 0; c0 < deg; c0 += 64) {
        if (c0 + lane < deg) {
            int e = eidx[start + c0 + lane];
#pragma unroll
            for (int h = 0; h < H; ++h) m[h] = fmaxf(m[h], esc[e * H + h]);
        }
    }
#pragma unroll
    for (int h = 0; h < H; ++h)
#pragma unroll
        for (int off = 32; off; off >>= 1) m[h] = fmaxf(m[h], __shfl_xor(m[h], off));
    for (int c0 = 0; c0 < deg; c0 += 64) {
        if (c0 + lane < deg) {
            int e = eidx[start + c0 + lane];
#pragma unroll
            for (int h = 0; h < H; ++h) s[h] += expf(esc[e * H + h] - m[h]);
        }
    }
#pragma unroll
    for (int h = 0; h < H; ++h)
#pragma unroll
        for (int off = 32; off; off >>= 1) s[h] += __shfl_xor(s[h], off);
    if (lane == 0) {
#pragma unroll
        for (int h = 0; h < H; ++h) {
            maxv[n * H + h] = m[h];
            den[n * H + h] = s[h] + 1e-9f;
        }
    }
}

// ---------------- per-dst weighted aggregation ----------------
// one 256-thread block per dst node. ACT: 0 = ELU -> bf16 out, 1 = sigmoid -> f32 out.
template <int ACT>
__global__ __launch_bounds__(256) void aggregate_kernel(
    const float* __restrict__ h, const float* __restrict__ esc,
    const int* __restrict__ offsets, const int* __restrict__ eidx,
    const int* __restrict__ src, const float* __restrict__ maxv,
    const float* __restrict__ den, const float* __restrict__ bias,
    void* __restrict__ out, int H, int F) {
    int n = blockIdx.x;
    int HF = H * F;
    int nvec = HF >> 2;
    int tid = threadIdx.x;
    int start = offsets[n];
    int deg = offsets[n + 1] - start;

    __shared__ int s_src[64];
    __shared__ float s_alpha[64 * 4];
    __shared__ float s_m[4], s_d[4];
    if (tid < H) { s_m[tid] = maxv[n * H + tid]; s_d[tid] = den[n * H + tid]; }
    __syncthreads();

    int hh = (tid * 4) / F;  // head of this vec4 (valid while tid < nvec)
    float4 acc = make_float4(0.f, 0.f, 0.f, 0.f);

    for (int c0 = 0; c0 < deg; c0 += 64) {
        int cn = min(64, deg - c0);
        if (tid < cn) {
            int e = eidx[start + c0 + tid];
            s_src[tid] = src[e];
            for (int h2 = 0; h2 < H; ++h2)
                s_alpha[tid * H + h2] = expf(esc[e * H + h2] - s_m[h2]) / s_d[h2];
        }
        __syncthreads();
        if (tid < nvec) {
            int k = 0;
            for (; k + 2 <= cn; k += 2) {
                const float4* r0 = (const float4*)(h + (size_t)s_src[k] * HF);
                const float4* r1 = (const float4*)(h + (size_t)s_src[k + 1] * HF);
                float a0 = s_alpha[k * H + hh];
                float a1 = s_alpha[(k + 1) * H + hh];
                float4 v0 = r0[tid];
                float4 v1 = r1[tid];
                acc.x += v0.x * a0 + v1.x * a1;
                acc.y += v0.y * a0 + v1.y * a1;
                acc.z += v0.z * a0 + v1.z * a1;
                acc.w += v0.w * a0 + v1.w * a1;
            }
            if (k < cn) {
                const float4* r0 = (const float4*)(h + (size_t)s_src[k] * HF);
                float a0 = s_alpha[k * H + hh];
                float4 v0 = r0[tid];
                acc.x += v0.x * a0;
                acc.y += v0.y * a0;
                acc.z += v0.z * a0;
                acc.w += v0.w * a0;
            }
        }
        __syncthreads();
    }

    if (tid < nvec) {
        float4 bb = ((const float4*)bias)[tid];
        float4 v;
        v.x = acc.x + bb.x; v.y = acc.y + bb.y; v.z = acc.z + bb.z; v.w = acc.w + bb.w;
        if (ACT == 0) {
            v.x = v.x > 0.f ? v.x : expm1f(v.x);
            v.y = v.y > 0.f ? v.y : expm1f(v.y);
            v.z = v.z > 0.f ? v.z : expm1f(v.z);
            v.w = v.w > 0.f ? v.w : expm1f(v.w);
            ushort4 u;
            u.x = f2b(v.x); u.y = f2b(v.y); u.z = f2b(v.z); u.w = f2b(v.w);
            ((ushort4*)out)[(size_t)n * nvec + tid] = u;
        } else {
            v.x = 1.f / (1.f + expf(-v.x));
            v.y = 1.f / (1.f + expf(-v.y));
            v.z = 1.f / (1.f + expf(-v.z));
            v.w = 1.f / (1.f + expf(-v.w));
            ((float4*)out)[(size_t)n * nvec + tid] = v;
        }
    }
}

// ---------------- launch ----------------

extern "C" void kernel_launch(void* const* d_in, const int* in_sizes, int n_in,
                              void* d_out, int out_size, void* d_ws, size_t ws_size,
                              hipStream_t stream) {
    const float* x   = (const float*)d_in[0];
    const int*   src = (const int*)d_in[1];
    const int*   dst = (const int*)d_in[2];
    const float* W1  = (const float*)d_in[3];
    const float* al1 = (const float*)d_in[4];
    const float* ar1 = (const float*)d_in[5];
    const float* b1  = (const float*)d_in[6];
    const float* W2  = (const float*)d_in[7];
    const float* al2 = (const float*)d_in[8];
    const float* ar2 = (const float*)d_in[9];
    const float* b2  = (const float*)d_in[10];
    const float* W3  = (const float*)d_in[11];
    const float* al3 = (const float*)d_in[12];
    const float* ar3 = (const float*)d_in[13];
    const float* b3  = (const float*)d_in[14];
    float* out = (float*)d_out;

    char* ws = (char*)d_ws;
    size_t off = 0;
    auto alloc = [&](size_t bytes) -> char* {
        char* p = ws + off;
        off += (bytes + 255) & ~(size_t)255;
        return p;
    };
    int* offsets = (int*)alloc((N_NODES + 1) * sizeof(int));
    int* cursor  = (int*)alloc(N_NODES * sizeof(int));
    int* deg     = (int*)alloc(N_NODES * sizeof(int));
    int* eidx    = (int*)alloc(N_EDGES * sizeof(int));
    float* el    = (float*)alloc((size_t)N_NODES * 4 * sizeof(float));
    float* er    = (float*)alloc((size_t)N_NODES * 4 * sizeof(float));
    float* maxv  = (float*)alloc((size_t)N_NODES * 4 * sizeof(float));
    float* denb  = (float*)alloc((size_t)N_NODES * 4 * sizeof(float));
    float* esc   = (float*)alloc((size_t)N_EDGES * 4 * sizeof(float));
    float* hbuf  = (float*)alloc((size_t)N_NODES * 800 * sizeof(float));         // GEMM out (fp32)
    unsigned short* Ab = (unsigned short*)alloc((size_t)N_NODES * 800 * 2);      // activations bf16
    unsigned short* Wt = (unsigned short*)alloc((size_t)800 * 400 * 2);          // W^T bf16 (max)

    // CSR build (dst-indexed)
    zero_ints<<<(N_NODES + 255) / 256, 256, 0, stream>>>(deg, N_NODES);
    zero_ints<<<(N_NODES + 255) / 256, 256, 0, stream>>>(cursor, N_NODES);
    hist_kernel<<<(N_EDGES + 255) / 256, 256, 0, stream>>>(dst, deg);
    scan_kernel<<<1, 256, 0, stream>>>(deg, offsets);
    scatter_kernel<<<(N_EDGES + 255) / 256, 256, 0, stream>>>(dst, offsets, cursor, eidx);

    // x -> bf16
    castx_kernel<<<(N_NODES * 128 / 4 + 255) / 256, 256, 0, stream>>>(x, Ab, N_NODES * 128 / 4);

    // ---- layer 1: [20000,128]x[128,400], H=4 F=100, ELU ----
    {
        int K = 128, N = 400, H = 4, F = 100;
        wcast_kernel<<<(K * N + 255) / 256, 256, 0, stream>>>(W1, Wt, K, N);
        dim3 grid((N + 63) / 64, (N_NODES + 127) / 128);
        gemm_mfma<<<grid, 256, 0, stream>>>(Ab, Wt, hbuf, N_NODES, N, K);
        elr_kernel<<<N_NODES, H * 64, 0, stream>>>(hbuf, al1, ar1, el, er, H, F);
        escore_kernel<<<(N_EDGES * H + 255) / 256, 256, 0, stream>>>(src, dst, el, er, esc, H);
        maxden_kernel<4><<<N_NODES, 64, 0, stream>>>(esc, offsets, eidx, maxv, denb);
        aggregate_kernel<0><<<N_NODES, 256, 0, stream>>>(hbuf, esc, offsets, eidx, src, maxv, denb, b1, Ab, H, F);
    }
    // ---- layer 2: [20000,400]x[400,800], H=4 F=200, ELU ----
    {
        int K = 400, N = 800, H = 4, F = 200;
        wcast_kernel<<<(K * N + 255) / 256, 256, 0, stream>>>(W2, Wt, K, N);
        dim3 grid((N + 63) / 64, (N_NODES + 127) / 128);
        gemm_mfma<<<grid, 256, 0, stream>>>(Ab, Wt, hbuf, N_NODES, N, K);
        elr_kernel<<<N_NODES, H * 64, 0, stream>>>(hbuf, al2, ar2, el, er, H, F);
        escore_kernel<<<(N_EDGES * H + 255) / 256, 256, 0, stream>>>(src, dst, el, er, esc, H);
        maxden_kernel<4><<<N_NODES, 64, 0, stream>>>(esc, offsets, eidx, maxv, denb);
        aggregate_kernel<0><<<N_NODES, 256, 0, stream>>>(hbuf, esc, offsets, eidx, src, maxv, denb, b2, Ab, H, F);
    }
    // ---- layer 3: [20000,800]x[800,64], H=1 F=64, sigmoid -> d_out ----
    {
        int K = 800, N = 64, H = 1, F = 64;
        wcast_kernel<<<(K * N + 255) / 256, 256, 0, stream>>>(W3, Wt, K, N);
        dim3 grid((N + 63) / 64, (N_NODES + 127) / 128);
        gemm_mfma<<<grid, 256, 0, stream>>>(Ab, Wt, hbuf, N_NODES, N, K);
        elr_kernel<<<N_NODES, H * 64, 0, stream>>>(hbuf, al3, ar3, el, er, H, F);
        escore_kernel<<<(N_EDGES * H + 255) / 256, 256, 0, stream>>>(src, dst, el, er, esc, H);
        maxden_kernel<1><<<N_NODES, 64, 0, stream>>>(esc, offsets, eidx, maxv, denb);
        aggregate_kernel<1><<<N_NODES, 256, 0, stream>>>(hbuf, esc, offsets, eidx, src, maxv, denb, b3, out, H, F);
    }
}

// Round 4
// 500.611 us; speedup vs baseline: 2.2990x; 1.2604x over previous
//
#include <hip/hip_runtime.h>
#include <math.h>

#define N_NODES 20000
#define N_EDGES 256000

typedef __attribute__((ext_vector_type(8))) short bf16x8;
typedef __attribute__((ext_vector_type(4))) float f32x4;

__device__ inline unsigned short f2b(float f) {
    unsigned u = __builtin_bit_cast(unsigned, f);
    unsigned r = (u + 0x7fffu + ((u >> 16) & 1u)) >> 16;
    return (unsigned short)r;
}
__device__ inline float b2f(unsigned short s) {
    return __builtin_bit_cast(float, ((unsigned)s) << 16);
}

// ---------------- CSR build ----------------

__global__ void zero_ints(int* __restrict__ a, int n) {
    int i = blockIdx.x * blockDim.x + threadIdx.x;
    if (i < n) a[i] = 0;
}

__global__ void hist_kernel(const int* __restrict__ dst, int* __restrict__ deg) {
    int i = blockIdx.x * blockDim.x + threadIdx.x;
    if (i < N_EDGES) atomicAdd(&deg[dst[i]], 1);
}

__global__ void scan_kernel(const int* __restrict__ deg, int* __restrict__ offsets) {
    __shared__ int red[256];
    __shared__ int s_total;
    int tid = threadIdx.x;
    if (tid == 0) { s_total = 0; offsets[0] = 0; }
    __syncthreads();
    for (int base = 0; base < N_NODES; base += 256) {
        int v = (base + tid < N_NODES) ? deg[base + tid] : 0;
        red[tid] = v;
        __syncthreads();
        for (int off = 1; off < 256; off <<= 1) {
            int t = (tid >= off) ? red[tid - off] : 0;
            __syncthreads();
            red[tid] += t;
            __syncthreads();
        }
        if (base + tid < N_NODES) offsets[base + tid + 1] = s_total + red[tid];
        __syncthreads();
        if (tid == 0) s_total += red[255];
        __syncthreads();
    }
}

// writes src id into CSR slot directly (no eidx indirection downstream)
__global__ void scatter_kernel(const int* __restrict__ dst, const int* __restrict__ src,
                               const int* __restrict__ offsets,
                               int* __restrict__ cursor, int* __restrict__ csrc) {
    int i = blockIdx.x * blockDim.x + threadIdx.x;
    if (i < N_EDGES) {
        int d = dst[i];
        int p = offsets[d] + atomicAdd(&cursor[d], 1);
        csrc[p] = src[i];
    }
}

// ---------------- casts ----------------

__global__ void castx_kernel(const float* __restrict__ in, unsigned short* __restrict__ out, int n4) {
    int i = blockIdx.x * blockDim.x + threadIdx.x;
    if (i < n4) {
        float4 v = ((const float4*)in)[i];
        ushort4 u;
        u.x = f2b(v.x); u.y = f2b(v.y); u.z = f2b(v.z); u.w = f2b(v.w);
        ((ushort4*)out)[i] = u;
    }
}

// Wt[n][k] = bf16(W[k][n]); W is [K][N] row-major
__global__ void wcast_kernel(const float* __restrict__ W, unsigned short* __restrict__ Wt,
                             int K, int N) {
    int id = blockIdx.x * blockDim.x + threadIdx.x;
    if (id < K * N) {
        int n = id / K, k = id - n * K;
        Wt[id] = f2b(W[(size_t)k * N + n]);
    }
}

// ---------------- bf16 MFMA GEMM: C[M,N](bf16) = A[M,K] * Bt[N,K]^T ----------------
// 128x64 tile, BK=32, 4 waves (2x2), per-wave 64x32 (4x2 frags of 16x16x32)

#define LDK 40  // 32 + 8 pad (bf16 elems)

__global__ __launch_bounds__(256) void gemm_mfma(
    const unsigned short* __restrict__ A, const unsigned short* __restrict__ Bt,
    unsigned short* __restrict__ C, int M, int N, int K) {
    __shared__ short As[128 * LDK];
    __shared__ short Bs[64 * LDK];
    int tid = threadIdx.x;
    int m0 = blockIdx.y * 128, n0 = blockIdx.x * 64;
    int lane = tid & 63, wid = tid >> 6;
    int wm = wid >> 1, wn = wid & 1;
    int r16 = lane & 15, kg = lane >> 4, k8 = kg * 8;

    f32x4 zero4 = {0.f, 0.f, 0.f, 0.f};
    f32x4 acc[4][2];
#pragma unroll
    for (int m = 0; m < 4; ++m)
#pragma unroll
        for (int nn = 0; nn < 2; ++nn) acc[m][nn] = zero4;

    bf16x8 zv = {0, 0, 0, 0, 0, 0, 0, 0};

    for (int k0 = 0; k0 < K; k0 += 32) {
#pragma unroll
        for (int i = 0; i < 2; ++i) {
            int c = tid + i * 256;
            int row = c >> 2, off = (c & 3) * 8;
            bf16x8 v = zv;
            int gr = m0 + row, gc = k0 + off;
            if (gr < M && gc + 8 <= K)
                v = *(const bf16x8*)(const void*)(A + (size_t)gr * K + gc);
            *(bf16x8*)(void*)(&As[row * LDK + off]) = v;
        }
        {
            int row = tid >> 2, off = (tid & 3) * 8;
            bf16x8 v = zv;
            int gr = n0 + row, gc = k0 + off;
            if (gr < N && gc + 8 <= K)
                v = *(const bf16x8*)(const void*)(Bt + (size_t)gr * K + gc);
            *(bf16x8*)(void*)(&Bs[row * LDK + off]) = v;
        }
        __syncthreads();
        bf16x8 a[4], b[2];
#pragma unroll
        for (int m = 0; m < 4; ++m)
            a[m] = *(const bf16x8*)(const void*)(&As[(wm * 64 + m * 16 + r16) * LDK + k8]);
#pragma unroll
        for (int nn = 0; nn < 2; ++nn)
            b[nn] = *(const bf16x8*)(const void*)(&Bs[(wn * 32 + nn * 16 + r16) * LDK + k8]);
#pragma unroll
        for (int m = 0; m < 4; ++m)
#pragma unroll
            for (int nn = 0; nn < 2; ++nn)
                acc[m][nn] = __builtin_amdgcn_mfma_f32_16x16x32_bf16(a[m], b[nn], acc[m][nn], 0, 0, 0);
        __syncthreads();
    }
#pragma unroll
    for (int m = 0; m < 4; ++m) {
        int row_base = m0 + wm * 64 + m * 16 + kg * 4;
#pragma unroll
        for (int nn = 0; nn < 2; ++nn) {
            int col = n0 + wn * 32 + nn * 16 + r16;
            if (col < N) {
#pragma unroll
                for (int r = 0; r < 4; ++r) {
                    int row = row_base + r;
                    if (row < M) C[(size_t)row * N + col] = f2b(acc[m][nn][r]);
                }
            }
        }
    }
}

// ---------------- attention left/right dot products (bf16 h) ----------------
__global__ void elr_kernel(const unsigned short* __restrict__ h, const float* __restrict__ al,
                           const float* __restrict__ ar, float* __restrict__ el,
                           float* __restrict__ er, int H, int F) {
    int n = blockIdx.x;
    int lane = threadIdx.x & 63;
    int hh = threadIdx.x >> 6;
    const unsigned short* row = h + (size_t)n * H * F + (size_t)hh * F;
    float sl = 0.f, sr = 0.f;
    for (int f = lane; f < F; f += 64) {
        float v = b2f(row[f]);
        sl += v * al[hh * F + f];
        sr += v * ar[hh * F + f];
    }
#pragma unroll
    for (int off = 32; off; off >>= 1) {
        sl += __shfl_down(sl, off);
        sr += __shfl_down(sr, off);
    }
    if (lane == 0) {
        el[n * H + hh] = sl;
        er[n * H + hh] = sr;
    }
}

// ---------------- fused edge-score + softmax -> alpha (CSR order) ----------------
// 4 waves / block, one node per wave.
template <int H>
__global__ __launch_bounds__(256) void alpha_kernel(
    const float* __restrict__ el, const float* __restrict__ er,
    const int* __restrict__ csrc, const int* __restrict__ offsets,
    float* __restrict__ alpha, int nnodes) {
    int n = blockIdx.x * 4 + (threadIdx.x >> 6);
    if (n >= nnodes) return;
    int lane = threadIdx.x & 63;
    int start = offsets[n], deg = offsets[n + 1] - start;
    if (deg == 0) return;
    float ern[H];
#pragma unroll
    for (int h = 0; h < H; ++h) ern[h] = er[n * H + h];

    if (deg <= 64) {
        bool act = lane < deg;
        float sh[H];
#pragma unroll
        for (int h = 0; h < H; ++h) sh[h] = -3.402823466e38f;
        if (act) {
            int sc = csrc[start + lane];
            if constexpr (H == 4) {
                float4 e4 = *(const float4*)(el + (size_t)sc * 4);
                float tv[4] = {e4.x, e4.y, e4.z, e4.w};
#pragma unroll
                for (int h = 0; h < 4; ++h) {
                    float v = tv[h] + ern[h];
                    sh[h] = v > 0.f ? v : 0.2f * v;
                }
            } else {
#pragma unroll
                for (int h = 0; h < H; ++h) {
                    float v = el[sc * H + h] + ern[h];
                    sh[h] = v > 0.f ? v : 0.2f * v;
                }
            }
        }
        float m[H], e[H], s[H];
#pragma unroll
        for (int h = 0; h < H; ++h) {
            m[h] = sh[h];
#pragma unroll
            for (int off = 32; off; off >>= 1) m[h] = fmaxf(m[h], __shfl_xor(m[h], off));
        }
#pragma unroll
        for (int h = 0; h < H; ++h) {
            e[h] = act ? expf(sh[h] - m[h]) : 0.f;
            s[h] = e[h];
#pragma unroll
            for (int off = 32; off; off >>= 1) s[h] += __shfl_xor(s[h], off);
        }
        if (act) {
            if constexpr (H == 4) {
                float4 o;
                o.x = e[0] / (s[0] + 1e-9f);
                o.y = e[1] / (s[1] + 1e-9f);
                o.z = e[2] / (s[2] + 1e-9f);
                o.w = e[3] / (s[3] + 1e-9f);
                *(float4*)(alpha + (size_t)(start + lane) * 4) = o;
            } else {
#pragma unroll
                for (int h = 0; h < H; ++h)
                    alpha[(size_t)(start + lane) * H + h] = e[h] / (s[h] + 1e-9f);
            }
        }
    } else {
        // general chunked 3-pass
        float m[H], s[H];
#pragma unroll
        for (int h = 0; h < H; ++h) { m[h] = -3.402823466e38f; s[h] = 0.f; }
        for (int c0 = 0; c0 < deg; c0 += 64) {
            if (c0 + lane < deg) {
                int sc = csrc[start + c0 + lane];
#pragma unroll
                for (int h = 0; h < H; ++h) {
                    float v = el[sc * H + h] + ern[h];
                    v = v > 0.f ? v : 0.2f * v;
                    m[h] = fmaxf(m[h], v);
                }
            }
        }
#pragma unroll
        for (int h = 0; h < H; ++h)
#pragma unroll
            for (int off = 32; off; off >>= 1) m[h] = fmaxf(m[h], __shfl_xor(m[h], off));
        for (int c0 = 0; c0 < deg; c0 += 64) {
            if (c0 + lane < deg) {
                int sc = csrc[start + c0 + lane];
#pragma unroll
                for (int h = 0; h < H; ++h) {
                    float v = el[sc * H + h] + ern[h];
                    v = v > 0.f ? v : 0.2f * v;
                    s[h] += expf(v - m[h]);
                }
            }
        }
#pragma unroll
        for (int h = 0; h < H; ++h)
#pragma unroll
            for (int off = 32; off; off >>= 1) s[h] += __shfl_xor(s[h], off);
        for (int c0 = 0; c0 < deg; c0 += 64) {
            if (c0 + lane < deg) {
                int sc = csrc[start + c0 + lane];
#pragma unroll
                for (int h = 0; h < H; ++h) {
                    float v = el[sc * H + h] + ern[h];
                    v = v > 0.f ? v : 0.2f * v;
                    alpha[(size_t)(start + c0 + lane) * H + h] = expf(v - m[h]) / (s[h] + 1e-9f);
                }
            }
        }
    }
}

// ---------------- per-dst weighted aggregation (bf16 gather) ----------------
// ACT: 0 = ELU -> bf16 out, 1 = sigmoid -> f32 out. NC = HF/8 chunks, P edges in flight.
template <int ACT, int H, int NC, int P>
__global__ __launch_bounds__(256) void aggregate_kernel(
    const unsigned short* __restrict__ hC, const float* __restrict__ alpha,
    const int* __restrict__ offsets, const int* __restrict__ csrc,
    const float* __restrict__ bias, void* __restrict__ out) {
    constexpr int HF = NC * 8;
    constexpr int F = HF / H;
    int n = blockIdx.x;
    int tid = threadIdx.x;
    int start = offsets[n], deg = offsets[n + 1] - start;

    __shared__ int s_src[64];
    __shared__ float s_alpha[64 * H];
    __shared__ float s_part[(P > 1 ? (P - 1) : 1) * NC * 8];

    bool active = tid < NC * P;
    int slot = tid % NC;
    int q = tid / NC;
    int h0 = (slot * 8) / F, h1 = (slot * 8 + 7) / F;
    int split = (h0 == h1) ? 8 : (h1 * F - slot * 8);
    float acc[8] = {0.f, 0.f, 0.f, 0.f, 0.f, 0.f, 0.f, 0.f};

    for (int c0 = 0; c0 < deg; c0 += 64) {
        int cn = min(64, deg - c0);
        if (tid < cn) {
            s_src[tid] = csrc[start + c0 + tid];
            if constexpr (H == 4) {
                float4 a4 = *(const float4*)(alpha + (size_t)(start + c0 + tid) * 4);
                *(float4*)(&s_alpha[tid * 4]) = a4;
            } else {
                s_alpha[tid] = alpha[start + c0 + tid];
            }
        }
        __syncthreads();
        if (active) {
            for (int k = q; k < cn; k += P) {
                const unsigned short* row = hC + (size_t)s_src[k] * HF;
                bf16x8 v = *(const bf16x8*)(const void*)(row + slot * 8);
                float a0 = s_alpha[k * H + h0];
                float a1 = s_alpha[k * H + h1];
#pragma unroll
                for (int j = 0; j < 8; ++j) {
                    float a = (j < split) ? a0 : a1;
                    acc[j] += b2f((unsigned short)v[j]) * a;
                }
            }
        }
        __syncthreads();
    }

    if constexpr (P > 1) {
        if (active && q > 0) {
#pragma unroll
            for (int j = 0; j < 8; ++j) s_part[((q - 1) * NC + slot) * 8 + j] = acc[j];
        }
        __syncthreads();
        if (tid < NC) {
            for (int qq = 1; qq < P; ++qq)
#pragma unroll
                for (int j = 0; j < 8; ++j) acc[j] += s_part[((qq - 1) * NC + slot) * 8 + j];
        }
    }

    if (tid < NC) {
        float4 bA = *(const float4*)(bias + slot * 8);
        float4 bB = *(const float4*)(bias + slot * 8 + 4);
        float bb[8] = {bA.x, bA.y, bA.z, bA.w, bB.x, bB.y, bB.z, bB.w};
        float v[8];
#pragma unroll
        for (int j = 0; j < 8; ++j) v[j] = acc[j] + bb[j];
        if (ACT == 0) {
            bf16x8 u;
#pragma unroll
            for (int j = 0; j < 8; ++j) {
                float w = v[j] > 0.f ? v[j] : expm1f(v[j]);
                u[j] = (short)f2b(w);
            }
            *(bf16x8*)(void*)((unsigned short*)out + (size_t)n * HF + slot * 8) = u;
        } else {
            float4 oA, oB;
            oA.x = 1.f / (1.f + expf(-v[0]));
            oA.y = 1.f / (1.f + expf(-v[1]));
            oA.z = 1.f / (1.f + expf(-v[2]));
            oA.w = 1.f / (1.f + expf(-v[3]));
            oB.x = 1.f / (1.f + expf(-v[4]));
            oB.y = 1.f / (1.f + expf(-v[5]));
            oB.z = 1.f / (1.f + expf(-v[6]));
            oB.w = 1.f / (1.f + expf(-v[7]));
            float* op = (float*)out + (size_t)n * HF + slot * 8;
            *(float4*)op = oA;
            *(float4*)(op + 4) = oB;
        }
    }
}

// ---------------- launch ----------------

extern "C" void kernel_launch(void* const* d_in, const int* in_sizes, int n_in,
                              void* d_out, int out_size, void* d_ws, size_t ws_size,
                              hipStream_t stream) {
    const float* x   = (const float*)d_in[0];
    const int*   src = (const int*)d_in[1];
    const int*   dst = (const int*)d_in[2];
    const float* W1  = (const float*)d_in[3];
    const float* al1 = (const float*)d_in[4];
    const float* ar1 = (const float*)d_in[5];
    const float* b1  = (const float*)d_in[6];
    const float* W2  = (const float*)d_in[7];
    const float* al2 = (const float*)d_in[8];
    const float* ar2 = (const float*)d_in[9];
    const float* b2  = (const float*)d_in[10];
    const float* W3  = (const float*)d_in[11];
    const float* al3 = (const float*)d_in[12];
    const float* ar3 = (const float*)d_in[13];
    const float* b3  = (const float*)d_in[14];
    float* out = (float*)d_out;

    char* ws = (char*)d_ws;
    size_t off = 0;
    auto alloc = [&](size_t bytes) -> char* {
        char* p = ws + off;
        off += (bytes + 255) & ~(size_t)255;
        return p;
    };
    int* offsets = (int*)alloc((N_NODES + 1) * sizeof(int));
    int* cursor  = (int*)alloc(N_NODES * sizeof(int));
    int* deg     = (int*)alloc(N_NODES * sizeof(int));
    int* csrc    = (int*)alloc(N_EDGES * sizeof(int));
    float* el    = (float*)alloc((size_t)N_NODES * 4 * sizeof(float));
    float* er    = (float*)alloc((size_t)N_NODES * 4 * sizeof(float));
    float* alpha = (float*)alloc((size_t)N_EDGES * 4 * sizeof(float));
    unsigned short* bufX = (unsigned short*)alloc((size_t)N_NODES * 800 * 2);  // layer input bf16
    unsigned short* bufH = (unsigned short*)alloc((size_t)N_NODES * 800 * 2);  // GEMM out (h) bf16
    unsigned short* Wt   = (unsigned short*)alloc((size_t)800 * 400 * 2);      // W^T bf16 (max)

    // CSR build (dst-indexed)
    zero_ints<<<(N_NODES + 255) / 256, 256, 0, stream>>>(deg, N_NODES);
    zero_ints<<<(N_NODES + 255) / 256, 256, 0, stream>>>(cursor, N_NODES);
    hist_kernel<<<(N_EDGES + 255) / 256, 256, 0, stream>>>(dst, deg);
    scan_kernel<<<1, 256, 0, stream>>>(deg, offsets);
    scatter_kernel<<<(N_EDGES + 255) / 256, 256, 0, stream>>>(dst, src, offsets, cursor, csrc);

    // x -> bf16
    castx_kernel<<<(N_NODES * 128 / 4 + 255) / 256, 256, 0, stream>>>(x, bufX, N_NODES * 128 / 4);

    // ---- layer 1: [20000,128]x[128,400], H=4 F=100, ELU ----
    {
        int K = 128, N = 400, H = 4, F = 100;
        wcast_kernel<<<(K * N + 255) / 256, 256, 0, stream>>>(W1, Wt, K, N);
        dim3 grid((N + 63) / 64, (N_NODES + 127) / 128);
        gemm_mfma<<<grid, 256, 0, stream>>>(bufX, Wt, bufH, N_NODES, N, K);
        elr_kernel<<<N_NODES, H * 64, 0, stream>>>(bufH, al1, ar1, el, er, H, F);
        alpha_kernel<4><<<(N_NODES + 3) / 4, 256, 0, stream>>>(el, er, csrc, offsets, alpha, N_NODES);
        aggregate_kernel<0, 4, 50, 4><<<N_NODES, 256, 0, stream>>>(bufH, alpha, offsets, csrc, b1, bufX);
    }
    // ---- layer 2: [20000,400]x[400,800], H=4 F=200, ELU ----
    {
        int K = 400, N = 800, H = 4, F = 200;
        wcast_kernel<<<(K * N + 255) / 256, 256, 0, stream>>>(W2, Wt, K, N);
        dim3 grid((N + 63) / 64, (N_NODES + 127) / 128);
        gemm_mfma<<<grid, 256, 0, stream>>>(bufX, Wt, bufH, N_NODES, N, K);
        elr_kernel<<<N_NODES, H * 64, 0, stream>>>(bufH, al2, ar2, el, er, H, F);
        alpha_kernel<4><<<(N_NODES + 3) / 4, 256, 0, stream>>>(el, er, csrc, offsets, alpha, N_NODES);
        aggregate_kernel<0, 4, 100, 2><<<N_NODES, 256, 0, stream>>>(bufH, alpha, offsets, csrc, b2, bufX);
    }
    // ---- layer 3: [20000,800]x[800,64], H=1 F=64, sigmoid -> d_out ----
    {
        int K = 800, N = 64, H = 1, F = 64;
        wcast_kernel<<<(K * N + 255) / 256, 256, 0, stream>>>(W3, Wt, K, N);
        dim3 grid((N + 63) / 64, (N_NODES + 127) / 128);
        gemm_mfma<<<grid, 256, 0, stream>>>(bufX, Wt, bufH, N_NODES, N, K);
        elr_kernel<<<N_NODES, 64, 0, stream>>>(bufH, al3, ar3, el, er, 1, F);
        alpha_kernel<1><<<(N_NODES + 3) / 4, 256, 0, stream>>>(el, er, csrc, offsets, alpha, N_NODES);
        aggregate_kernel<1, 1, 8, 8><<<N_NODES, 256, 0, stream>>>(bufH, alpha, offsets, csrc, b3, out);
    }
}

// Round 5
// 424.775 us; speedup vs baseline: 2.7094x; 1.1785x over previous
//
#include <hip/hip_runtime.h>
#include <math.h>

#define N_NODES 20000
#define N_EDGES 256000

typedef __attribute__((ext_vector_type(8))) short bf16x8;
typedef __attribute__((ext_vector_type(4))) float f32x4;

__device__ inline unsigned short f2b(float f) {
    unsigned u = __builtin_bit_cast(unsigned, f);
    unsigned r = (u + 0x7fffu + ((u >> 16) & 1u)) >> 16;
    return (unsigned short)r;
}
__device__ inline float b2f(unsigned short s) {
    return __builtin_bit_cast(float, ((unsigned)s) << 16);
}

// ---------------- CSR build ----------------

__global__ void zero_ints(int* __restrict__ a, int n) {
    int i = blockIdx.x * blockDim.x + threadIdx.x;
    if (i < n) a[i] = 0;
}

__global__ void hist_kernel(const int* __restrict__ dst, int* __restrict__ deg) {
    int i = blockIdx.x * blockDim.x + threadIdx.x;
    if (i < N_EDGES) atomicAdd(&deg[dst[i]], 1);
}

// one-pass single-block scan: 1024 threads x 20-elem chunks, 20 barriers total.
#define SCAN_T 1024
#define SCAN_CH 20  // ceil(N_NODES / SCAN_T)

__global__ __launch_bounds__(1024) void scan_kernel(const int* __restrict__ deg,
                                                    int* __restrict__ offsets) {
    __shared__ int sums[SCAN_T];
    int tid = threadIdx.x;
    int base = tid * SCAN_CH;
    int vals[SCAN_CH];
    int local = 0;
#pragma unroll
    for (int i = 0; i < SCAN_CH; ++i) {
        int idx = base + i;
        int v = (idx < N_NODES) ? deg[idx] : 0;
        vals[i] = v;
        local += v;
    }
    sums[tid] = local;
    __syncthreads();
    for (int off = 1; off < SCAN_T; off <<= 1) {
        int t = (tid >= off) ? sums[tid - off] : 0;
        __syncthreads();
        sums[tid] += t;
        __syncthreads();
    }
    int run = (tid > 0) ? sums[tid - 1] : 0;
    if (tid == 0) offsets[0] = 0;
#pragma unroll
    for (int i = 0; i < SCAN_CH; ++i) {
        int idx = base + i;
        if (idx < N_NODES) {
            run += vals[i];
            offsets[idx + 1] = run;
        }
    }
}

// writes src id into CSR slot directly
__global__ void scatter_kernel(const int* __restrict__ dst, const int* __restrict__ src,
                               const int* __restrict__ offsets,
                               int* __restrict__ cursor, int* __restrict__ csrc) {
    int i = blockIdx.x * blockDim.x + threadIdx.x;
    if (i < N_EDGES) {
        int d = dst[i];
        int p = offsets[d] + atomicAdd(&cursor[d], 1);
        csrc[p] = src[i];
    }
}

// ---------------- casts ----------------

__global__ void castx_kernel(const float* __restrict__ in, unsigned short* __restrict__ out, int n4) {
    int i = blockIdx.x * blockDim.x + threadIdx.x;
    if (i < n4) {
        float4 v = ((const float4*)in)[i];
        ushort4 u;
        u.x = f2b(v.x); u.y = f2b(v.y); u.z = f2b(v.z); u.w = f2b(v.w);
        ((ushort4*)out)[i] = u;
    }
}

// Wt[n][k] = bf16(W[k][n]); W is [K][N] row-major
__global__ void wcast_kernel(const float* __restrict__ W, unsigned short* __restrict__ Wt,
                             int K, int N) {
    int id = blockIdx.x * blockDim.x + threadIdx.x;
    if (id < K * N) {
        int n = id / K, k = id - n * K;
        Wt[id] = f2b(W[(size_t)k * N + n]);
    }
}

// ---------------- bf16 MFMA GEMM: C[M,N](bf16) = A[M,K] * Bt[N,K]^T ----------------

#define LDK 40  // 32 + 8 pad (bf16 elems)

__global__ __launch_bounds__(256) void gemm_mfma(
    const unsigned short* __restrict__ A, const unsigned short* __restrict__ Bt,
    unsigned short* __restrict__ C, int M, int N, int K) {
    __shared__ short As[128 * LDK];
    __shared__ short Bs[64 * LDK];
    int tid = threadIdx.x;
    int m0 = blockIdx.y * 128, n0 = blockIdx.x * 64;
    int lane = tid & 63, wid = tid >> 6;
    int wm = wid >> 1, wn = wid & 1;
    int r16 = lane & 15, kg = lane >> 4, k8 = kg * 8;

    f32x4 zero4 = {0.f, 0.f, 0.f, 0.f};
    f32x4 acc[4][2];
#pragma unroll
    for (int m = 0; m < 4; ++m)
#pragma unroll
        for (int nn = 0; nn < 2; ++nn) acc[m][nn] = zero4;

    bf16x8 zv = {0, 0, 0, 0, 0, 0, 0, 0};

    for (int k0 = 0; k0 < K; k0 += 32) {
#pragma unroll
        for (int i = 0; i < 2; ++i) {
            int c = tid + i * 256;
            int row = c >> 2, off = (c & 3) * 8;
            bf16x8 v = zv;
            int gr = m0 + row, gc = k0 + off;
            if (gr < M && gc + 8 <= K)
                v = *(const bf16x8*)(const void*)(A + (size_t)gr * K + gc);
            *(bf16x8*)(void*)(&As[row * LDK + off]) = v;
        }
        {
            int row = tid >> 2, off = (tid & 3) * 8;
            bf16x8 v = zv;
            int gr = n0 + row, gc = k0 + off;
            if (gr < N && gc + 8 <= K)
                v = *(const bf16x8*)(const void*)(Bt + (size_t)gr * K + gc);
            *(bf16x8*)(void*)(&Bs[row * LDK + off]) = v;
        }
        __syncthreads();
        bf16x8 a[4], b[2];
#pragma unroll
        for (int m = 0; m < 4; ++m)
            a[m] = *(const bf16x8*)(const void*)(&As[(wm * 64 + m * 16 + r16) * LDK + k8]);
#pragma unroll
        for (int nn = 0; nn < 2; ++nn)
            b[nn] = *(const bf16x8*)(const void*)(&Bs[(wn * 32 + nn * 16 + r16) * LDK + k8]);
#pragma unroll
        for (int m = 0; m < 4; ++m)
#pragma unroll
            for (int nn = 0; nn < 2; ++nn)
                acc[m][nn] = __builtin_amdgcn_mfma_f32_16x16x32_bf16(a[m], b[nn], acc[m][nn], 0, 0, 0);
        __syncthreads();
    }
#pragma unroll
    for (int m = 0; m < 4; ++m) {
        int row_base = m0 + wm * 64 + m * 16 + kg * 4;
#pragma unroll
        for (int nn = 0; nn < 2; ++nn) {
            int col = n0 + wn * 32 + nn * 16 + r16;
            if (col < N) {
#pragma unroll
                for (int r = 0; r < 4; ++r) {
                    int row = row_base + r;
                    if (row < M) C[(size_t)row * N + col] = f2b(acc[m][nn][r]);
                }
            }
        }
    }
}

// ---------------- attention left/right dot products (packed uint loads) ----------------
__global__ void elr_kernel(const unsigned short* __restrict__ h, const float* __restrict__ al,
                           const float* __restrict__ ar, float* __restrict__ el,
                           float* __restrict__ er, int H, int F) {
    int n = blockIdx.x;
    int lane = threadIdx.x & 63;
    int hh = threadIdx.x >> 6;
    const unsigned* row = (const unsigned*)(const void*)(h + (size_t)n * H * F + (size_t)hh * F);
    int F2 = F >> 1;
    float sl = 0.f, sr = 0.f;
    for (int f = lane; f < F2; f += 64) {
        unsigned u = row[f];
        float v0 = b2f((unsigned short)(u & 0xffffu));
        float v1 = b2f((unsigned short)(u >> 16));
        int c = hh * F + 2 * f;
        sl += v0 * al[c] + v1 * al[c + 1];
        sr += v0 * ar[c] + v1 * ar[c + 1];
    }
#pragma unroll
    for (int off = 32; off; off >>= 1) {
        sl += __shfl_down(sl, off);
        sr += __shfl_down(sr, off);
    }
    if (lane == 0) {
        el[n * H + hh] = sl;
        er[n * H + hh] = sr;
    }
}

// ---------------- fused edge-score + softmax -> alpha (CSR order) ----------------
template <int H>
__global__ __launch_bounds__(256) void alpha_kernel(
    const float* __restrict__ el, const float* __restrict__ er,
    const int* __restrict__ csrc, const int* __restrict__ offsets,
    float* __restrict__ alpha, int nnodes) {
    int n = blockIdx.x * 4 + (threadIdx.x >> 6);
    if (n >= nnodes) return;
    int lane = threadIdx.x & 63;
    int start = offsets[n], deg = offsets[n + 1] - start;
    if (deg == 0) return;
    float ern[H];
#pragma unroll
    for (int h = 0; h < H; ++h) ern[h] = er[n * H + h];

    if (deg <= 64) {
        bool act = lane < deg;
        float sh[H];
#pragma unroll
        for (int h = 0; h < H; ++h) sh[h] = -3.402823466e38f;
        if (act) {
            int sc = csrc[start + lane];
            if constexpr (H == 4) {
                float4 e4 = *(const float4*)(el + (size_t)sc * 4);
                float tv[4] = {e4.x, e4.y, e4.z, e4.w};
#pragma unroll
                for (int h = 0; h < 4; ++h) {
                    float v = tv[h] + ern[h];
                    sh[h] = v > 0.f ? v : 0.2f * v;
                }
            } else {
#pragma unroll
                for (int h = 0; h < H; ++h) {
                    float v = el[sc * H + h] + ern[h];
                    sh[h] = v > 0.f ? v : 0.2f * v;
                }
            }
        }
        float m[H], e[H], s[H];
#pragma unroll
        for (int h = 0; h < H; ++h) {
            m[h] = sh[h];
#pragma unroll
            for (int off = 32; off; off >>= 1) m[h] = fmaxf(m[h], __shfl_xor(m[h], off));
        }
#pragma unroll
        for (int h = 0; h < H; ++h) {
            e[h] = act ? expf(sh[h] - m[h]) : 0.f;
            s[h] = e[h];
#pragma unroll
            for (int off = 32; off; off >>= 1) s[h] += __shfl_xor(s[h], off);
        }
        if (act) {
            if constexpr (H == 4) {
                float4 o;
                o.x = e[0] / (s[0] + 1e-9f);
                o.y = e[1] / (s[1] + 1e-9f);
                o.z = e[2] / (s[2] + 1e-9f);
                o.w = e[3] / (s[3] + 1e-9f);
                *(float4*)(alpha + (size_t)(start + lane) * 4) = o;
            } else {
#pragma unroll
                for (int h = 0; h < H; ++h)
                    alpha[(size_t)(start + lane) * H + h] = e[h] / (s[h] + 1e-9f);
            }
        }
    } else {
        float m[H], s[H];
#pragma unroll
        for (int h = 0; h < H; ++h) { m[h] = -3.402823466e38f; s[h] = 0.f; }
        for (int c0 = 0; c0 < deg; c0 += 64) {
            if (c0 + lane < deg) {
                int sc = csrc[start + c0 + lane];
#pragma unroll
                for (int h = 0; h < H; ++h) {
                    float v = el[sc * H + h] + ern[h];
                    v = v > 0.f ? v : 0.2f * v;
                    m[h] = fmaxf(m[h], v);
                }
            }
        }
#pragma unroll
        for (int h = 0; h < H; ++h)
#pragma unroll
            for (int off = 32; off; off >>= 1) m[h] = fmaxf(m[h], __shfl_xor(m[h], off));
        for (int c0 = 0; c0 < deg; c0 += 64) {
            if (c0 + lane < deg) {
                int sc = csrc[start + c0 + lane];
#pragma unroll
                for (int h = 0; h < H; ++h) {
                    float v = el[sc * H + h] + ern[h];
                    v = v > 0.f ? v : 0.2f * v;
                    s[h] += expf(v - m[h]);
                }
            }
        }
#pragma unroll
        for (int h = 0; h < H; ++h)
#pragma unroll
            for (int off = 32; off; off >>= 1) s[h] += __shfl_xor(s[h], off);
        for (int c0 = 0; c0 < deg; c0 += 64) {
            if (c0 + lane < deg) {
                int sc = csrc[start + c0 + lane];
#pragma unroll
                for (int h = 0; h < H; ++h) {
                    float v = el[sc * H + h] + ern[h];
                    v = v > 0.f ? v : 0.2f * v;
                    alpha[(size_t)(start + c0 + lane) * H + h] = expf(v - m[h]) / (s[h] + 1e-9f);
                }
            }
        }
    }
}

// ---------------- per-dst weighted aggregation (bf16 gather) ----------------
template <int ACT, int H, int NC, int P>
__global__ __launch_bounds__(256) void aggregate_kernel(
    const unsigned short* __restrict__ hC, const float* __restrict__ alpha,
    const int* __restrict__ offsets, const int* __restrict__ csrc,
    const float* __restrict__ bias, void* __restrict__ out) {
    constexpr int HF = NC * 8;
    constexpr int F = HF / H;
    int n = blockIdx.x;
    int tid = threadIdx.x;
    int start = offsets[n], deg = offsets[n + 1] - start;

    __shared__ int s_src[64];
    __shared__ float s_alpha[64 * H];
    __shared__ float s_part[(P > 1 ? (P - 1) : 1) * NC * 8];

    bool active = tid < NC * P;
    int slot = tid % NC;
    int q = tid / NC;
    int h0 = (slot * 8) / F, h1 = (slot * 8 + 7) / F;
    int split = (h0 == h1) ? 8 : (h1 * F - slot * 8);
    float acc[8] = {0.f, 0.f, 0.f, 0.f, 0.f, 0.f, 0.f, 0.f};

    for (int c0 = 0; c0 < deg; c0 += 64) {
        int cn = min(64, deg - c0);
        if (tid < cn) {
            s_src[tid] = csrc[start + c0 + tid];
            if constexpr (H == 4) {
                float4 a4 = *(const float4*)(alpha + (size_t)(start + c0 + tid) * 4);
                *(float4*)(&s_alpha[tid * 4]) = a4;
            } else {
                s_alpha[tid] = alpha[start + c0 + tid];
            }
        }
        __syncthreads();
        if (active) {
            for (int k = q; k < cn; k += P) {
                const unsigned short* row = hC + (size_t)s_src[k] * HF;
                bf16x8 v = *(const bf16x8*)(const void*)(row + slot * 8);
                float a0 = s_alpha[k * H + h0];
                float a1 = s_alpha[k * H + h1];
#pragma unroll
                for (int j = 0; j < 8; ++j) {
                    float a = (j < split) ? a0 : a1;
                    acc[j] += b2f((unsigned short)v[j]) * a;
                }
            }
        }
        __syncthreads();
    }

    if constexpr (P > 1) {
        if (active && q > 0) {
#pragma unroll
            for (int j = 0; j < 8; ++j) s_part[((q - 1) * NC + slot) * 8 + j] = acc[j];
        }
        __syncthreads();
        if (tid < NC) {
            for (int qq = 1; qq < P; ++qq)
#pragma unroll
                for (int j = 0; j < 8; ++j) acc[j] += s_part[((qq - 1) * NC + slot) * 8 + j];
        }
    }

    if (tid < NC) {
        float4 bA = *(const float4*)(bias + slot * 8);
        float4 bB = *(const float4*)(bias + slot * 8 + 4);
        float bb[8] = {bA.x, bA.y, bA.z, bA.w, bB.x, bB.y, bB.z, bB.w};
        float v[8];
#pragma unroll
        for (int j = 0; j < 8; ++j) v[j] = acc[j] + bb[j];
        if (ACT == 0) {
            bf16x8 u;
#pragma unroll
            for (int j = 0; j < 8; ++j) {
                float w = v[j] > 0.f ? v[j] : expm1f(v[j]);
                u[j] = (short)f2b(w);
            }
            *(bf16x8*)(void*)((unsigned short*)out + (size_t)n * HF + slot * 8) = u;
        } else {
            float4 oA, oB;
            oA.x = 1.f / (1.f + expf(-v[0]));
            oA.y = 1.f / (1.f + expf(-v[1]));
            oA.z = 1.f / (1.f + expf(-v[2]));
            oA.w = 1.f / (1.f + expf(-v[3]));
            oB.x = 1.f / (1.f + expf(-v[4]));
            oB.y = 1.f / (1.f + expf(-v[5]));
            oB.z = 1.f / (1.f + expf(-v[6]));
            oB.w = 1.f / (1.f + expf(-v[7]));
            float* op = (float*)out + (size_t)n * HF + slot * 8;
            *(float4*)op = oA;
            *(float4*)(op + 4) = oB;
        }
    }
}

// ---------------- launch ----------------

extern "C" void kernel_launch(void* const* d_in, const int* in_sizes, int n_in,
                              void* d_out, int out_size, void* d_ws, size_t ws_size,
                              hipStream_t stream) {
    const float* x   = (const float*)d_in[0];
    const int*   src = (const int*)d_in[1];
    const int*   dst = (const int*)d_in[2];
    const float* W1  = (const float*)d_in[3];
    const float* al1 = (const float*)d_in[4];
    const float* ar1 = (const float*)d_in[5];
    const float* b1  = (const float*)d_in[6];
    const float* W2  = (const float*)d_in[7];
    const float* al2 = (const float*)d_in[8];
    const float* ar2 = (const float*)d_in[9];
    const float* b2  = (const float*)d_in[10];
    const float* W3  = (const float*)d_in[11];
    const float* al3 = (const float*)d_in[12];
    const float* ar3 = (const float*)d_in[13];
    const float* b3  = (const float*)d_in[14];
    float* out = (float*)d_out;

    char* ws = (char*)d_ws;
    size_t off = 0;
    auto alloc = [&](size_t bytes) -> char* {
        char* p = ws + off;
        off += (bytes + 255) & ~(size_t)255;
        return p;
    };
    int* offsets = (int*)alloc((N_NODES + 1) * sizeof(int));
    int* cursor  = (int*)alloc(N_NODES * sizeof(int));
    int* deg     = (int*)alloc(N_NODES * sizeof(int));
    int* csrc    = (int*)alloc(N_EDGES * sizeof(int));
    float* el    = (float*)alloc((size_t)N_NODES * 4 * sizeof(float));
    float* er    = (float*)alloc((size_t)N_NODES * 4 * sizeof(float));
    float* alpha = (float*)alloc((size_t)N_EDGES * 4 * sizeof(float));
    unsigned short* bufX = (unsigned short*)alloc((size_t)N_NODES * 800 * 2);
    unsigned short* bufH = (unsigned short*)alloc((size_t)N_NODES * 800 * 2);
    unsigned short* Wt   = (unsigned short*)alloc((size_t)800 * 400 * 2);

    // CSR build (dst-indexed)
    zero_ints<<<(N_NODES + 255) / 256, 256, 0, stream>>>(deg, N_NODES);
    zero_ints<<<(N_NODES + 255) / 256, 256, 0, stream>>>(cursor, N_NODES);
    hist_kernel<<<(N_EDGES + 255) / 256, 256, 0, stream>>>(dst, deg);
    scan_kernel<<<1, SCAN_T, 0, stream>>>(deg, offsets);
    scatter_kernel<<<(N_EDGES + 255) / 256, 256, 0, stream>>>(dst, src, offsets, cursor, csrc);

    // x -> bf16
    castx_kernel<<<(N_NODES * 128 / 4 + 255) / 256, 256, 0, stream>>>(x, bufX, N_NODES * 128 / 4);

    // ---- layer 1: [20000,128]x[128,400], H=4 F=100, ELU ----
    {
        int K = 128, N = 400, H = 4, F = 100;
        wcast_kernel<<<(K * N + 255) / 256, 256, 0, stream>>>(W1, Wt, K, N);
        dim3 grid((N + 63) / 64, (N_NODES + 127) / 128);
        gemm_mfma<<<grid, 256, 0, stream>>>(bufX, Wt, bufH, N_NODES, N, K);
        elr_kernel<<<N_NODES, H * 64, 0, stream>>>(bufH, al1, ar1, el, er, H, F);
        alpha_kernel<4><<<(N_NODES + 3) / 4, 256, 0, stream>>>(el, er, csrc, offsets, alpha, N_NODES);
        aggregate_kernel<0, 4, 50, 4><<<N_NODES, 256, 0, stream>>>(bufH, alpha, offsets, csrc, b1, bufX);
    }
    // ---- layer 2: [20000,400]x[400,800], H=4 F=200, ELU ----
    {
        int K = 400, N = 800, H = 4, F = 200;
        wcast_kernel<<<(K * N + 255) / 256, 256, 0, stream>>>(W2, Wt, K, N);
        dim3 grid((N + 63) / 64, (N_NODES + 127) / 128);
        gemm_mfma<<<grid, 256, 0, stream>>>(bufX, Wt, bufH, N_NODES, N, K);
        elr_kernel<<<N_NODES, H * 64, 0, stream>>>(bufH, al2, ar2, el, er, H, F);
        alpha_kernel<4><<<(N_NODES + 3) / 4, 256, 0, stream>>>(el, er, csrc, offsets, alpha, N_NODES);
        aggregate_kernel<0, 4, 100, 2><<<N_NODES, 256, 0, stream>>>(bufH, alpha, offsets, csrc, b2, bufX);
    }
    // ---- layer 3: [20000,800]x[800,64], H=1 F=64, sigmoid -> d_out ----
    {
        int K = 800, N = 64, H = 1, F = 64;
        wcast_kernel<<<(K * N + 255) / 256, 256, 0, stream>>>(W3, Wt, K, N);
        dim3 grid((N + 63) / 64, (N_NODES + 127) / 128);
        gemm_mfma<<<grid, 256, 0, stream>>>(bufX, Wt, bufH, N_NODES, N, K);
        elr_kernel<<<N_NODES, 64, 0, stream>>>(bufH, al3, ar3, el, er, 1, F);
        alpha_kernel<1><<<(N_NODES + 3) / 4, 256, 0, stream>>>(el, er, csrc, offsets, alpha, N_NODES);
        aggregate_kernel<1, 1, 8, 8><<<N_NODES, 256, 0, stream>>>(bufH, alpha, offsets, csrc, b3, out);
    }
}